// Round 8
// baseline (731.637 us; speedup 1.0000x reference)
//
#include <hip/hip_runtime.h>
#include <hip/hip_bf16.h>

#define HDIM 512
#define BDIM 1024
#define DDIM 256

typedef _Float16 half8 __attribute__((ext_vector_type(8)));
typedef float f32x4 __attribute__((ext_vector_type(4)));

__device__ __forceinline__ float ftanh(float x) {
    // tanh(x) = 1 - 2/(exp(2x)+1); raw v_rcp (rel err ~1e-6, fine vs 0.094 thr)
    float e = __expf(2.0f * x);
    float d = e + 1.0f;
    float r;
    asm("v_rcp_f32 %0, %1" : "=v"(r) : "v"(d));
    return 1.0f - 2.0f * r;
}

// K0: Wah f32 [512][512] -> W16 fp16, linear-stream layout:
// granule n = chunk*1024 + kb*64 + kp*16 + g  holds Wah[chunk*16+g][kb*32+kp*8 ..+8].
// A wave reading granule (step*64 + lane) gets, for step = chunk*16+kb:
// g = lane&15, k-part = lane>>4  == exactly the 16x16x32 B-fragment, and the
// per-wave load is 1024 consecutive bytes -> perfectly coalesced, L1-broadcast
// across the 8 waves of a block.
__global__ __launch_bounds__(256) void k_convertW(const float* __restrict__ Wah,
                                                  _Float16* __restrict__ W16) {
    int n = blockIdx.x * 256 + threadIdx.x;   // granule id, 32768 total
    int chunk = n >> 10, r = n & 1023;
    int kb = r >> 6, kp = (r >> 4) & 3, g = r & 15;
    const float* src = Wah + (size_t)(chunk * 16 + g) * 512 + kb * 32 + kp * 8;
    float4 v0 = *(const float4*)src;
    float4 v1 = *(const float4*)(src + 4);
    half8 h;
    h[0] = (_Float16)v0.x; h[1] = (_Float16)v0.y; h[2] = (_Float16)v0.z; h[3] = (_Float16)v0.w;
    h[4] = (_Float16)v1.x; h[5] = (_Float16)v1.y; h[6] = (_Float16)v1.z; h[7] = (_Float16)v1.w;
    *(half8*)&W16[(size_t)n * 8] = h;
}

// K1: qb[b,g] = concat(h_tilde,c_t)[b,:] . Waq[g,:] + ba[g]   (fp32)
__global__ __launch_bounds__(256) void k_qproj(const float* __restrict__ h_tilde,
                                               const float* __restrict__ c_t,
                                               const float* __restrict__ Waq,
                                               const float* __restrict__ ba,
                                               float* __restrict__ qb) {
    __shared__ float qs[4][1024];
    int t = threadIdx.x;
    int b0 = blockIdx.x * 4;
    #pragma unroll
    for (int p = 0; p < 4; p++) {
        int f4 = t + p * 256;
        int e = f4 * 4;
        int row = e >> 10, k = e & 1023;
        float4 v;
        if (k < 512) v = *(const float4*)&h_tilde[(b0 + row) * 512 + k];
        else         v = *(const float4*)&c_t[(b0 + row) * 512 + k - 512];
        *(float4*)&qs[row][k] = v;
    }
    __syncthreads();
    int g0 = t, g1 = t + 256;
    float acc0[4] = {0.f, 0.f, 0.f, 0.f};
    float acc1[4] = {0.f, 0.f, 0.f, 0.f};
    const float4* w0p = (const float4*)&Waq[(size_t)g0 * 1024];
    const float4* w1p = (const float4*)&Waq[(size_t)g1 * 1024];
    #pragma unroll 4
    for (int k4 = 0; k4 < 256; k4++) {
        float4 w0 = w0p[k4];
        float4 w1 = w1p[k4];
        #pragma unroll
        for (int bb = 0; bb < 4; bb++) {
            float4 q = *(const float4*)&qs[bb][k4 * 4];
            acc0[bb] += q.x * w0.x + q.y * w0.y + q.z * w0.z + q.w * w0.w;
            acc1[bb] += q.x * w1.x + q.y * w1.y + q.z * w1.z + q.w * w1.w;
        }
    }
    #pragma unroll
    for (int bb = 0; bb < 4; bb++) {
        qb[(b0 + bb) * 512 + g0] = acc0[bb] + ba[g0];
        qb[(b0 + bb) * 512 + g1] = acc1[bb] + ba[g1];
    }
}

// K2 (fused, barrier-free main loop): one block per b, 512 thr / 8 waves,
// wave owns 32 of the 256 rows. X = hist[b] in registers (fp16 A-frags,
// loaded once). W streamed PER-WAVE from global (L1-broadcast across waves)
// through an 8-deep register ring -- NO LDS for W, NO barriers until the
// epilogue. Per 16-col chunk: 32 MFMA (4 independent 8-deep chains) ->
// tanh+qb -> .v fold. Then in-block softmax + e_t from the afr registers.
__global__ __launch_bounds__(512, 2) void k_fused(const float* __restrict__ hist,
                                                  const float* __restrict__ qb,
                                                  const _Float16* __restrict__ W16,
                                                  const float* __restrict__ v_t,
                                                  float* __restrict__ out) {
    __shared__ float qbs[512];
    __shared__ float vsh[512];
    __shared__ float lsh[256];
    __shared__ float ash[256];
    __shared__ float wredM[8];
    __shared__ float wredS[8];
    __shared__ float esh[8][512];

    int t = threadIdx.x;
    int w = t >> 6, lane = t & 63, l15 = lane & 15, l4 = lane >> 4;
    int b = blockIdx.x;
    size_t m_base = (size_t)b * 256;

    qbs[t] = qb[b * 512 + t];
    vsh[t] = v_t[t];
    __syncthreads();   // before any VMEM: drain is free; last barrier until epilogue

    // X-load: afr[mf][kb] = hist[b][w*32 + mf*16 + l15][kb*32 + l4*8 .. +8] fp16
    half8 afr[2][16];
    const float* xb = hist + (m_base + w * 32 + l15) * 512 + l4 * 8;
    #pragma unroll
    for (int kb = 0; kb < 16; kb++) {
        #pragma unroll
        for (int mf = 0; mf < 2; mf++) {
            const float* p = xb + mf * 16 * 512 + kb * 32;
            float4 v0 = *(const float4*)p;
            float4 v1 = *(const float4*)(p + 4);
            half8 h;
            h[0] = (_Float16)v0.x; h[1] = (_Float16)v0.y; h[2] = (_Float16)v0.z; h[3] = (_Float16)v0.w;
            h[4] = (_Float16)v1.x; h[5] = (_Float16)v1.y; h[6] = (_Float16)v1.z; h[7] = (_Float16)v1.w;
            afr[mf][kb] = h;
        }
    }

    // W ring: step s (= c*16+kb) lives at granules [s*64, s*64+64); lane's
    // granule = s*64 + lane. Prefetch depth 8 (8 KB in flight per wave).
    // NOTE: last chunk prefetches steps 512..519 -> reads 8 KB of pad after
    // W16 (never consumed); ws provides it.
    const half8* wl = (const half8*)W16 + lane;
    half8 ring[8];
    #pragma unroll
    for (int u = 0; u < 8; u++) ring[u] = wl[u * 64];
    const half8* wn = wl + 8 * 64;

    float S[2][4] = {{0.f, 0.f, 0.f, 0.f}, {0.f, 0.f, 0.f, 0.f}};

    #pragma unroll 1
    for (int c = 0; c < 32; c++) {
        float qv = qbs[c * 16 + l15];     // issued early, used after MFMAs
        float vv = vsh[c * 16 + l15];
        f32x4 a00 = (f32x4){0.f, 0.f, 0.f, 0.f};
        f32x4 a01 = (f32x4){0.f, 0.f, 0.f, 0.f};
        f32x4 a10 = (f32x4){0.f, 0.f, 0.f, 0.f};
        f32x4 a11 = (f32x4){0.f, 0.f, 0.f, 0.f};
        #pragma unroll
        for (int kb = 0; kb < 16; kb++) {
            half8 bf = ring[kb & 7];
            ring[kb & 7] = wn[kb * 64];   // prefetch step c*16+kb+8
            if (kb & 1) {
                a01 = __builtin_amdgcn_mfma_f32_16x16x32_f16(afr[0][kb], bf, a01, 0, 0, 0);
                a11 = __builtin_amdgcn_mfma_f32_16x16x32_f16(afr[1][kb], bf, a11, 0, 0, 0);
            } else {
                a00 = __builtin_amdgcn_mfma_f32_16x16x32_f16(afr[0][kb], bf, a00, 0, 0, 0);
                a10 = __builtin_amdgcn_mfma_f32_16x16x32_f16(afr[1][kb], bf, a10, 0, 0, 0);
            }
        }
        wn += 16 * 64;
        #pragma unroll
        for (int j = 0; j < 4; j++) {
            S[0][j] += ftanh(a00[j] + a01[j] + qv) * vv;
            S[1][j] += ftanh(a10[j] + a11[j] + qv) * vv;
        }
    }

    // ---- logits: reduce S over l15 ----
    #pragma unroll
    for (int mf = 0; mf < 2; mf++) {
        #pragma unroll
        for (int j = 0; j < 4; j++) {
            float s = S[mf][j];
            s += __shfl_xor(s, 1, 64);
            s += __shfl_xor(s, 2, 64);
            s += __shfl_xor(s, 4, 64);
            s += __shfl_xor(s, 8, 64);
            if (l15 == 0) lsh[w * 32 + mf * 16 + l4 * 4 + j] = s;
        }
    }
    __syncthreads();

    // ---- softmax over D=256 (waves 4-7 mirror 0-3) ----
    float lv = lsh[t & 255];
    float m = lv;
    m = fmaxf(m, __shfl_xor(m, 1, 64));
    m = fmaxf(m, __shfl_xor(m, 2, 64));
    m = fmaxf(m, __shfl_xor(m, 4, 64));
    m = fmaxf(m, __shfl_xor(m, 8, 64));
    m = fmaxf(m, __shfl_xor(m, 16, 64));
    m = fmaxf(m, __shfl_xor(m, 32, 64));
    if (lane == 0 && w < 4) wredM[w] = m;
    __syncthreads();
    m = fmaxf(fmaxf(wredM[0], wredM[1]), fmaxf(wredM[2], wredM[3]));
    float e = __expf(lv - m);
    float ssum = e;
    ssum += __shfl_xor(ssum, 1, 64);
    ssum += __shfl_xor(ssum, 2, 64);
    ssum += __shfl_xor(ssum, 4, 64);
    ssum += __shfl_xor(ssum, 8, 64);
    ssum += __shfl_xor(ssum, 16, 64);
    ssum += __shfl_xor(ssum, 32, 64);
    if (lane == 0 && w < 4) wredS[w] = ssum;
    __syncthreads();
    ssum = wredS[0] + wredS[1] + wredS[2] + wredS[3];
    float a = e / ssum;
    if (t < 256) {
        ash[t] = a;
        out[BDIM * HDIM + b * 256 + t] = a;   // alpha
    }
    __syncthreads();

    // ---- e_t from afr: e_t[h] = sum_d alpha[d] * X16[d][h] ----
    float al0 = ash[w * 32 + l15];
    float al1 = ash[w * 32 + 16 + l15];
    #pragma unroll
    for (int kb = 0; kb < 16; kb++) {
        float ep[8];
        half8 x0 = afr[0][kb];
        half8 x1 = afr[1][kb];
        #pragma unroll
        for (int e2 = 0; e2 < 8; e2++)
            ep[e2] = al0 * (float)x0[e2] + al1 * (float)x1[e2];
        #pragma unroll
        for (int e2 = 0; e2 < 8; e2++) {
            ep[e2] += __shfl_xor(ep[e2], 1, 64);
            ep[e2] += __shfl_xor(ep[e2], 2, 64);
            ep[e2] += __shfl_xor(ep[e2], 4, 64);
            ep[e2] += __shfl_xor(ep[e2], 8, 64);
        }
        if (l15 == 0) {
            #pragma unroll
            for (int e2 = 0; e2 < 8; e2++)
                esh[w][kb * 32 + l4 * 8 + e2] = ep[e2];
        }
    }
    __syncthreads();
    float r = 0.f;
    #pragma unroll
    for (int ww = 0; ww < 8; ww++) r += esh[ww][t];
    out[(size_t)b * 512 + t] = r;   // e_t
}

extern "C" void kernel_launch(void* const* d_in, const int* in_sizes, int n_in,
                              void* d_out, int out_size, void* d_ws, size_t ws_size,
                              hipStream_t stream) {
    const float* h_tilde = (const float*)d_in[0];
    const float* c_t     = (const float*)d_in[1];
    const float* hist    = (const float*)d_in[2];
    const float* Waq     = (const float*)d_in[3];
    const float* Wah     = (const float*)d_in[4];
    const float* ba      = (const float*)d_in[5];
    const float* v_t     = (const float*)d_in[6];
    float* out = (float*)d_out;

    char* ws = (char*)d_ws;
    float*    qb  = (float*)ws;                               // 2 MB
    _Float16* W16 = (_Float16*)(ws + (2u << 20));             // 512 KB (+8 KB pad read-only)

    k_convertW<<<128, 256, 0, stream>>>(Wah, W16);
    k_qproj<<<256, 256, 0, stream>>>(h_tilde, c_t, Waq, ba, qb);
    k_fused<<<1024, 512, 0, stream>>>(hist, qb, W16, v_t, out);
}

// Round 9
// 556.088 us; speedup vs baseline: 1.3157x; 1.3157x over previous
//
#include <hip/hip_runtime.h>
#include <hip/hip_bf16.h>

#define HDIM 512
#define BDIM 1024
#define DDIM 256
#define MTOT (BDIM * DDIM)

typedef _Float16 half8 __attribute__((ext_vector_type(8)));
typedef float f32x4 __attribute__((ext_vector_type(4)));

__device__ __forceinline__ float ftanh(float x) {
    float e = __expf(2.0f * x);
    return 1.0f - 2.0f / (e + 1.0f);
}

__device__ __forceinline__ void gl_lds16(const _Float16* src, _Float16* dst) {
    __builtin_amdgcn_global_load_lds((const __attribute__((address_space(1))) void*)src,
                                     (__attribute__((address_space(3))) void*)dst,
                                     16, 0, 0);
}

// K0: Wah f32 [512][512] -> W16 fp16, per-(nb,ks) 16 KB chunks.
// Within chunk: granule (cb*64 + kp*16 + cl) holds Wah[nb*256 + cb*16 + cl][ks*32 + kp*8 ..+8].
// => linear DMA image; B-frag j of wave w reads granules (w*4+j)*64 + lane:
//    64 consecutive granules per wave -> zero bank conflicts (R7-measured).
__global__ __launch_bounds__(256) void k_convertW(const float* __restrict__ Wah,
                                                  _Float16* __restrict__ W16) {
    int n = blockIdx.x * 256 + threadIdx.x;   // granule id, 32768 total
    int chunk = n >> 10;                      // (nb*16 + ks)
    int nb = chunk >> 4, ks = chunk & 15;
    int r = n & 1023;
    int cb = r >> 6, kp = (r >> 4) & 3, cl = r & 15;
    int g = nb * 256 + cb * 16 + cl;
    const float* src = Wah + (size_t)g * 512 + ks * 32 + kp * 8;
    float4 v0 = *(const float4*)src;
    float4 v1 = *(const float4*)(src + 4);
    half8 h;
    h[0] = (_Float16)v0.x; h[1] = (_Float16)v0.y; h[2] = (_Float16)v0.z; h[3] = (_Float16)v0.w;
    h[4] = (_Float16)v1.x; h[5] = (_Float16)v1.y; h[6] = (_Float16)v1.z; h[7] = (_Float16)v1.w;
    *(half8*)&W16[(size_t)n * 8] = h;
}

// K1: qb[b,g] = concat(h_tilde,c_t)[b,:] . Waq[g,:] + ba[g]   (fp32)
__global__ __launch_bounds__(256) void k_qproj(const float* __restrict__ h_tilde,
                                               const float* __restrict__ c_t,
                                               const float* __restrict__ Waq,
                                               const float* __restrict__ ba,
                                               float* __restrict__ qb) {
    __shared__ float qs[4][1024];
    int t = threadIdx.x;
    int b0 = blockIdx.x * 4;
    #pragma unroll
    for (int p = 0; p < 4; p++) {
        int f4 = t + p * 256;
        int e = f4 * 4;
        int row = e >> 10, k = e & 1023;
        float4 v;
        if (k < 512) v = *(const float4*)&h_tilde[(b0 + row) * 512 + k];
        else         v = *(const float4*)&c_t[(b0 + row) * 512 + k - 512];
        *(float4*)&qs[row][k] = v;
    }
    __syncthreads();
    int g0 = t, g1 = t + 256;
    float acc0[4] = {0.f, 0.f, 0.f, 0.f};
    float acc1[4] = {0.f, 0.f, 0.f, 0.f};
    const float4* w0p = (const float4*)&Waq[(size_t)g0 * 1024];
    const float4* w1p = (const float4*)&Waq[(size_t)g1 * 1024];
    #pragma unroll 4
    for (int k4 = 0; k4 < 256; k4++) {
        float4 w0 = w0p[k4];
        float4 w1 = w1p[k4];
        #pragma unroll
        for (int bb = 0; bb < 4; bb++) {
            float4 q = *(const float4*)&qs[bb][k4 * 4];
            acc0[bb] += q.x * w0.x + q.y * w0.y + q.z * w0.z + q.w * w0.w;
            acc1[bb] += q.x * w1.x + q.y * w1.y + q.z * w1.z + q.w * w1.w;
        }
    }
    #pragma unroll
    for (int bb = 0; bb < 4; bb++) {
        qb[(b0 + bb) * 512 + g0] = acc0[bb] + ba[g0];
        qb[(b0 + bb) * 512 + g1] = acc1[bb] + ba[g1];
    }
}

// K2: partial logits. Block = 128 m-rows x 256 cols (nb half), 256 thr/4 waves.
// N-SPLIT waves: wave w owns ALL 128 rows x cols [w*64, w*64+64).
// X streamed through LDS (fragment-linear layout, conflict-free reads+writes),
// W chunks via linear global_load_lds DMA (conflict-free reads). Double-buffered,
// one __syncthreads per K-step; 2 blocks/CU overlap each other's drains.
__global__ __launch_bounds__(256, 2) void k_logits(const float* __restrict__ hist,
                                                   const float* __restrict__ qb,
                                                   const _Float16* __restrict__ W16,
                                                   const float* __restrict__ v_t,
                                                   float* __restrict__ logitsP) {
    __shared__ _Float16 Xb[2][4096];   // 8 KB each
    __shared__ _Float16 Wb[2][8192];   // 16 KB each
    __shared__ float qbs[256];
    __shared__ float vsh[256];
    __shared__ float red[4][128];

    int t = threadIdx.x;
    int w = t >> 6, lane = t & 63, l15 = lane & 15, l4 = lane >> 4;
    int bx = blockIdx.x, mt = bx >> 1, nb = bx & 1;
    size_t m_base = (size_t)mt * 128;
    int b = mt >> 1;                    // 128-row tile within one b (D=256)

    qbs[t] = qb[b * 512 + nb * 256 + t];
    vsh[t] = v_t[nb * 256 + t];

    const _Float16* wbase = W16 + (size_t)nb * 16 * 8192;   // + s*8192 per step

    // X staging ownership: lane l of wave w stages rows ra=32w+l15 (granule a)
    // and rb=ra+16 (granule b), k-part kp=l4. LDS granules {w*128+l, w*128+64+l}
    // are CONSECUTIVE per wave per write -> conflict-free ds_write_b128.
    const float* xsrc_a = hist + (m_base + w * 32 + l15) * 512 + l4 * 8;
    const float* xsrc_b = xsrc_a + 16 * 512;
    const int gpos_a = (w * 128 + lane) * 8;
    const int gpos_b = (w * 128 + 64 + lane) * 8;

    // ---- prologue: W-DMA(0), X(0) load+stage ----
    #pragma unroll
    for (int sg = 0; sg < 4; sg++)
        gl_lds16(wbase + ((size_t)(w * 4 + sg) * 64 + lane) * 8,
                 &Wb[0][(w * 4 + sg) * 512]);
    float4 xa0 = *(const float4*)(xsrc_a);
    float4 xa1 = *(const float4*)(xsrc_a + 4);
    float4 xb0 = *(const float4*)(xsrc_b);
    float4 xb1 = *(const float4*)(xsrc_b + 4);
    {
        half8 ha, hb;
        ha[0] = (_Float16)xa0.x; ha[1] = (_Float16)xa0.y; ha[2] = (_Float16)xa0.z; ha[3] = (_Float16)xa0.w;
        ha[4] = (_Float16)xa1.x; ha[5] = (_Float16)xa1.y; ha[6] = (_Float16)xa1.z; ha[7] = (_Float16)xa1.w;
        hb[0] = (_Float16)xb0.x; hb[1] = (_Float16)xb0.y; hb[2] = (_Float16)xb0.z; hb[3] = (_Float16)xb0.w;
        hb[4] = (_Float16)xb1.x; hb[5] = (_Float16)xb1.y; hb[6] = (_Float16)xb1.z; hb[7] = (_Float16)xb1.w;
        *(half8*)&Xb[0][gpos_a] = ha;
        *(half8*)&Xb[0][gpos_b] = hb;
    }
    __syncthreads();

    f32x4 acc[8][4];
    #pragma unroll
    for (int i = 0; i < 8; i++)
        #pragma unroll
        for (int j = 0; j < 4; j++)
            acc[i][j] = (f32x4){0.f, 0.f, 0.f, 0.f};

    for (int s = 0; s < 16; s++) {
        int cur = s & 1;
        if (s < 15) {
            // issue next W chunk DMA (dest buf's readers finished before iter s)
            const _Float16* wc = wbase + (size_t)(s + 1) * 8192;
            _Float16* wd = Wb[cur ^ 1];
            #pragma unroll
            for (int sg = 0; sg < 4; sg++)
                gl_lds16(wc + ((size_t)(w * 4 + sg) * 64 + lane) * 8,
                         &wd[(w * 4 + sg) * 512]);
            // issue next X global loads (consumed after compute below)
            const float* pa = xsrc_a + (s + 1) * 32;
            const float* pb = xsrc_b + (s + 1) * 32;
            xa0 = *(const float4*)(pa);
            xa1 = *(const float4*)(pa + 4);
            xb0 = *(const float4*)(pb);
            xb1 = *(const float4*)(pb + 4);
        }
        // ---- compute(s): conflict-free consecutive-granule ds_reads ----
        const _Float16* xp = Xb[cur];
        const _Float16* wp = Wb[cur];
        half8 bfr[4];
        #pragma unroll
        for (int j = 0; j < 4; j++)
            bfr[j] = *(const half8*)&wp[((w * 4 + j) * 64 + lane) * 8];
        #pragma unroll
        for (int i = 0; i < 8; i++) {
            half8 af = *(const half8*)&xp[(i * 64 + lane) * 8];
            #pragma unroll
            for (int j = 0; j < 4; j++)
                acc[i][j] = __builtin_amdgcn_mfma_f32_16x16x32_f16(af, bfr[j], acc[i][j], 0, 0, 0);
        }
        // ---- stage X(s+1) (buffer's last readers finished before iter s) ----
        if (s < 15) {
            half8 ha, hb;
            ha[0] = (_Float16)xa0.x; ha[1] = (_Float16)xa0.y; ha[2] = (_Float16)xa0.z; ha[3] = (_Float16)xa0.w;
            ha[4] = (_Float16)xa1.x; ha[5] = (_Float16)xa1.y; ha[6] = (_Float16)xa1.z; ha[7] = (_Float16)xa1.w;
            hb[0] = (_Float16)xb0.x; hb[1] = (_Float16)xb0.y; hb[2] = (_Float16)xb0.z; hb[3] = (_Float16)xb0.w;
            hb[4] = (_Float16)xb1.x; hb[5] = (_Float16)xb1.y; hb[6] = (_Float16)xb1.z; hb[7] = (_Float16)xb1.w;
            _Float16* xd = Xb[cur ^ 1];
            *(half8*)&xd[gpos_a] = ha;
            *(half8*)&xd[gpos_b] = hb;
        }
        __syncthreads();   // W-DMA(s+1) + X writes drained; all waves done reading
    }

    // ---- fold: tanh + v-dot over this wave's 64 cols ----
    // C/D map: row = i*16 + l4*4 + r, col = w*64 + j*16 + l15
    float qv[4], vv[4];
    #pragma unroll
    for (int j = 0; j < 4; j++) {
        qv[j] = qbs[w * 64 + j * 16 + l15];
        vv[j] = vsh[w * 64 + j * 16 + l15];
    }
    #pragma unroll
    for (int i = 0; i < 8; i++) {
        #pragma unroll
        for (int r = 0; r < 4; r++) {
            float s = 0.0f;
            #pragma unroll
            for (int j = 0; j < 4; j++)
                s += ftanh(acc[i][j][r] + qv[j]) * vv[j];
            s += __shfl_xor(s, 1, 64);
            s += __shfl_xor(s, 2, 64);
            s += __shfl_xor(s, 4, 64);
            s += __shfl_xor(s, 8, 64);
            if (l15 == 0) red[w][i * 16 + l4 * 4 + r] = s;
        }
    }
    __syncthreads();
    if (t < 128)
        logitsP[(size_t)nb * MTOT + m_base + t] =
            red[0][t] + red[1][t] + red[2][t] + red[3][t];
}

// K3: per-b softmax over D=256 (combining nb partials) + e_t = alpha @ hist[b]
__global__ __launch_bounds__(256) void k_softmax_et(const float* __restrict__ hist,
                                                    const float* __restrict__ logitsP,
                                                    float* __restrict__ out) {
    __shared__ float as_[256];
    __shared__ float wred[4];
    __shared__ float ered[512];
    int b = blockIdx.x, t = threadIdx.x;
    float l = logitsP[b * 256 + t] + logitsP[MTOT + b * 256 + t];
    float m = l;
    m = fmaxf(m, __shfl_xor(m, 1, 64));
    m = fmaxf(m, __shfl_xor(m, 2, 64));
    m = fmaxf(m, __shfl_xor(m, 4, 64));
    m = fmaxf(m, __shfl_xor(m, 8, 64));
    m = fmaxf(m, __shfl_xor(m, 16, 64));
    m = fmaxf(m, __shfl_xor(m, 32, 64));
    if ((t & 63) == 0) wred[t >> 6] = m;
    __syncthreads();
    m = fmaxf(fmaxf(wred[0], wred[1]), fmaxf(wred[2], wred[3]));
    float e = __expf(l - m);
    float s = e;
    s += __shfl_xor(s, 1, 64);
    s += __shfl_xor(s, 2, 64);
    s += __shfl_xor(s, 4, 64);
    s += __shfl_xor(s, 8, 64);
    s += __shfl_xor(s, 16, 64);
    s += __shfl_xor(s, 32, 64);
    __syncthreads();
    if ((t & 63) == 0) wred[t >> 6] = s;
    __syncthreads();
    s = wred[0] + wred[1] + wred[2] + wred[3];
    float a = e / s;
    out[BDIM * HDIM + b * 256 + t] = a;      // alpha
    as_[t] = a;
    __syncthreads();
    int c4 = (t & 127) * 4;
    int dp = t >> 7;
    float e0 = 0.f, e1 = 0.f, e2 = 0.f, e3 = 0.f;
    const float* hb = hist + (size_t)b * 256 * 512 + c4;
    #pragma unroll 4
    for (int d = dp; d < 256; d += 2) {
        float al = as_[d];
        float4 h = *(const float4*)&hb[(size_t)d * 512];
        e0 += al * h.x; e1 += al * h.y; e2 += al * h.z; e3 += al * h.w;
    }
    if (dp) {
        float4 v; v.x = e0; v.y = e1; v.z = e2; v.w = e3;
        *(float4*)&ered[c4] = v;
    }
    __syncthreads();
    if (!dp) {
        float4 p = *(const float4*)&ered[c4];
        float4 r; r.x = e0 + p.x; r.y = e1 + p.y; r.z = e2 + p.z; r.w = e3 + p.w;
        *(float4*)&out[b * 512 + c4] = r;
    }
}

extern "C" void kernel_launch(void* const* d_in, const int* in_sizes, int n_in,
                              void* d_out, int out_size, void* d_ws, size_t ws_size,
                              hipStream_t stream) {
    const float* h_tilde = (const float*)d_in[0];
    const float* c_t     = (const float*)d_in[1];
    const float* hist    = (const float*)d_in[2];
    const float* Waq     = (const float*)d_in[3];
    const float* Wah     = (const float*)d_in[4];
    const float* ba      = (const float*)d_in[5];
    const float* v_t     = (const float*)d_in[6];
    float* out = (float*)d_out;

    char* ws = (char*)d_ws;
    float*    qb      = (float*)ws;                               // 2 MB
    _Float16* W16     = (_Float16*)(ws + (2u << 20));             // 512 KB
    float*    logitsP = (float*)(ws + (3u << 20));                // 2 MB

    k_convertW<<<128, 256, 0, stream>>>(Wah, W16);
    k_qproj<<<256, 256, 0, stream>>>(h_tilde, c_t, Waq, ba, qb);
    k_logits<<<4096, 256, 0, stream>>>(hist, qb, W16, v_t, logitsP);
    k_softmax_et<<<1024, 256, 0, stream>>>(hist, logitsP, out);
}

// Round 10
// 414.449 us; speedup vs baseline: 1.7653x; 1.3418x over previous
//
#include <hip/hip_runtime.h>
#include <hip/hip_bf16.h>

#define HDIM 512
#define BDIM 1024
#define DDIM 256
#define MTOT (BDIM * DDIM)

typedef _Float16 half8 __attribute__((ext_vector_type(8)));
typedef float f32x4 __attribute__((ext_vector_type(4)));

__device__ __forceinline__ float ftanh(float x) {
    float e = __expf(2.0f * x);
    return 1.0f - 2.0f / (e + 1.0f);
}

__device__ __forceinline__ void gl_lds16(const _Float16* src, _Float16* dst) {
    __builtin_amdgcn_global_load_lds((const __attribute__((address_space(1))) void*)src,
                                     (__attribute__((address_space(3))) void*)dst,
                                     16, 0, 0);
}

// K0: Wah f32 [512][512] -> W16 fp16 chunked (R7 layout, measured 0 conflicts).
// Chunk c = g-cols [c*16, c*16+16), 8192 halves contiguous. Granule
// kb*64 + kp*16 + g holds Wah[c*16+g][kb*32 + kp*8 .. +8]. B-frag for lane l
// sits at granule kb*64 + l -> wave reads 1024 consecutive bytes.
__global__ __launch_bounds__(256) void k_convertW(const float* __restrict__ Wah,
                                                  _Float16* __restrict__ W16) {
    int n = blockIdx.x * 256 + threadIdx.x;   // granule id, 32768 total
    int chunk = n >> 10, r = n & 1023;
    int kb = r >> 6, kp = (r >> 4) & 3, g = r & 15;
    const float* src = Wah + (size_t)(chunk * 16 + g) * 512 + kb * 32 + kp * 8;
    float4 v0 = *(const float4*)src;
    float4 v1 = *(const float4*)(src + 4);
    half8 h;
    h[0] = (_Float16)v0.x; h[1] = (_Float16)v0.y; h[2] = (_Float16)v0.z; h[3] = (_Float16)v0.w;
    h[4] = (_Float16)v1.x; h[5] = (_Float16)v1.y; h[6] = (_Float16)v1.z; h[7] = (_Float16)v1.w;
    *(half8*)&W16[(size_t)n * 8] = h;
}

// K1: qb[b,g] = concat(h_tilde,c_t)[b,:] . Waq[g,:] + ba[g]   (fp32)
__global__ __launch_bounds__(256) void k_qproj(const float* __restrict__ h_tilde,
                                               const float* __restrict__ c_t,
                                               const float* __restrict__ Waq,
                                               const float* __restrict__ ba,
                                               float* __restrict__ qb) {
    __shared__ float qs[4][1024];
    int t = threadIdx.x;
    int b0 = blockIdx.x * 4;
    #pragma unroll
    for (int p = 0; p < 4; p++) {
        int f4 = t + p * 256;
        int e = f4 * 4;
        int row = e >> 10, k = e & 1023;
        float4 v;
        if (k < 512) v = *(const float4*)&h_tilde[(b0 + row) * 512 + k];
        else         v = *(const float4*)&c_t[(b0 + row) * 512 + k - 512];
        *(float4*)&qs[row][k] = v;
    }
    __syncthreads();
    int g0 = t, g1 = t + 256;
    float acc0[4] = {0.f, 0.f, 0.f, 0.f};
    float acc1[4] = {0.f, 0.f, 0.f, 0.f};
    const float4* w0p = (const float4*)&Waq[(size_t)g0 * 1024];
    const float4* w1p = (const float4*)&Waq[(size_t)g1 * 1024];
    #pragma unroll 4
    for (int k4 = 0; k4 < 256; k4++) {
        float4 w0 = w0p[k4];
        float4 w1 = w1p[k4];
        #pragma unroll
        for (int bb = 0; bb < 4; bb++) {
            float4 q = *(const float4*)&qs[bb][k4 * 4];
            acc0[bb] += q.x * w0.x + q.y * w0.y + q.z * w0.z + q.w * w0.w;
            acc1[bb] += q.x * w1.x + q.y * w1.y + q.z * w1.z + q.w * w1.w;
        }
    }
    #pragma unroll
    for (int bb = 0; bb < 4; bb++) {
        qb[(b0 + bb) * 512 + g0] = acc0[bb] + ba[g0];
        qb[(b0 + bb) * 512 + g1] = acc1[bb] + ba[g1];
    }
}

// K2: logits[m] = sum_g tanh((hist @ Wah.T)[m,g] + qb[b,g]) * v[g]
// R5 structure, HALF the per-wave state for occupancy: block = 64 rows x
// full N=512, 4 waves, wave owns 16 rows (afr[16] = 64 VGPR). W streamed
// through LDS in 32 chunks (16 g x 512 k = 16 KB, dbuf, linear DMA).
// launch_bounds(256,4): ~4 blocks/CU co-resident -> 16 waves/CU hide the
// per-chunk barrier drains with other blocks' MFMA work.
__global__ __launch_bounds__(256, 4) void k_logits(const float* __restrict__ hist,
                                                   const float* __restrict__ qb,
                                                   const _Float16* __restrict__ W16,
                                                   const float* __restrict__ v_t,
                                                   float* __restrict__ logits) {
    __shared__ _Float16 Wb[2][8192];   // 16 KB each
    __shared__ float qbs[512];
    __shared__ float vsh[512];

    int t = threadIdx.x;
    int w = t >> 6, lane = t & 63, l15 = lane & 15, l4 = lane >> 4;
    size_t m_base = (size_t)blockIdx.x * 64;
    int b = blockIdx.x >> 2;           // 64-row tile within one b (D=256)

    qbs[t] = qb[b * 512 + t];
    qbs[t + 256] = qb[b * 512 + 256 + t];
    vsh[t] = v_t[t];
    vsh[t + 256] = v_t[256 + t];

    // issue DMA for chunk 0 (completes during X-load phase)
    #pragma unroll
    for (int sg = 0; sg < 4; sg++)
        gl_lds16(W16 + ((size_t)(w * 4 + sg) * 64 + lane) * 8,
                 &Wb[0][(w * 4 + sg) * 512]);

    // X-load: afr[kb] = hist[m_base + w*16 + l15][kb*32 + l4*8 .. +8] as fp16
    half8 afr[16];
    const float* xb = hist + (m_base + w * 16 + l15) * 512 + l4 * 8;
    #pragma unroll
    for (int kb = 0; kb < 16; kb++) {
        const float* p = xb + kb * 32;
        float4 v0 = *(const float4*)p;
        float4 v1 = *(const float4*)(p + 4);
        half8 h;
        h[0] = (_Float16)v0.x; h[1] = (_Float16)v0.y; h[2] = (_Float16)v0.z; h[3] = (_Float16)v0.w;
        h[4] = (_Float16)v1.x; h[5] = (_Float16)v1.y; h[6] = (_Float16)v1.z; h[7] = (_Float16)v1.w;
        afr[kb] = h;
    }

    float S[4] = {0.f, 0.f, 0.f, 0.f};

    __syncthreads();   // drains DMA chunk 0 + qbs/vsh stores

    const _Float16* bufbase0 = &Wb[0][lane * 8];
    const _Float16* bufbase1 = &Wb[1][lane * 8];

    for (int c = 0; c < 32; c++) {
        int cur = c & 1;
        if (c < 31) {
            const _Float16* wc = W16 + (size_t)(c + 1) * 8192;
            _Float16* wd = Wb[cur ^ 1];
            #pragma unroll
            for (int sg = 0; sg < 4; sg++)
                gl_lds16(wc + ((size_t)(w * 4 + sg) * 64 + lane) * 8,
                         &wd[(w * 4 + sg) * 512]);
        }
        const _Float16* bufp = cur ? bufbase1 : bufbase0;
        f32x4 tac = (f32x4){0.f, 0.f, 0.f, 0.f};
        __builtin_amdgcn_s_setprio(1);
        #pragma unroll
        for (int kb = 0; kb < 16; kb++) {
            half8 bf = *(const half8*)(bufp + kb * 512);
            tac = __builtin_amdgcn_mfma_f32_16x16x32_f16(afr[kb], bf, tac, 0, 0, 0);
        }
        __builtin_amdgcn_s_setprio(0);
        float qv = qbs[c * 16 + l15];
        float vv = vsh[c * 16 + l15];
        #pragma unroll
        for (int j = 0; j < 4; j++)
            S[j] += ftanh(tac[j] + qv) * vv;
        __syncthreads();   // DMA(c+1) done; all waves done with buf[cur]
    }

    // reduce over l15; C/D map: row = l4*4 + j (within wave's 16 rows)
    #pragma unroll
    for (int j = 0; j < 4; j++) {
        float s = S[j];
        s += __shfl_xor(s, 1, 64);
        s += __shfl_xor(s, 2, 64);
        s += __shfl_xor(s, 4, 64);
        s += __shfl_xor(s, 8, 64);
        if (l15 == 0)
            logits[m_base + w * 16 + l4 * 4 + j] = s;
    }
}

// K3: per-b softmax over D=256 + e_t = alpha @ hist[b]   (fp32, memory-bound)
__global__ __launch_bounds__(256) void k_softmax_et(const float* __restrict__ hist,
                                                    const float* __restrict__ logits,
                                                    float* __restrict__ out) {
    __shared__ float as_[256];
    __shared__ float wred[4];
    __shared__ float ered[512];
    int b = blockIdx.x, t = threadIdx.x;
    float l = logits[b * 256 + t];
    float m = l;
    m = fmaxf(m, __shfl_xor(m, 1, 64));
    m = fmaxf(m, __shfl_xor(m, 2, 64));
    m = fmaxf(m, __shfl_xor(m, 4, 64));
    m = fmaxf(m, __shfl_xor(m, 8, 64));
    m = fmaxf(m, __shfl_xor(m, 16, 64));
    m = fmaxf(m, __shfl_xor(m, 32, 64));
    if ((t & 63) == 0) wred[t >> 6] = m;
    __syncthreads();
    m = fmaxf(fmaxf(wred[0], wred[1]), fmaxf(wred[2], wred[3]));
    float e = __expf(l - m);
    float s = e;
    s += __shfl_xor(s, 1, 64);
    s += __shfl_xor(s, 2, 64);
    s += __shfl_xor(s, 4, 64);
    s += __shfl_xor(s, 8, 64);
    s += __shfl_xor(s, 16, 64);
    s += __shfl_xor(s, 32, 64);
    __syncthreads();
    if ((t & 63) == 0) wred[t >> 6] = s;
    __syncthreads();
    s = wred[0] + wred[1] + wred[2] + wred[3];
    float a = e / s;
    out[BDIM * HDIM + b * 256 + t] = a;      // alpha
    as_[t] = a;
    __syncthreads();
    int c4 = (t & 127) * 4;
    int dp = t >> 7;
    float e0 = 0.f, e1 = 0.f, e2 = 0.f, e3 = 0.f;
    const float* hb = hist + (size_t)b * 256 * 512 + c4;
    #pragma unroll 4
    for (int d = dp; d < 256; d += 2) {
        float al = as_[d];
        float4 h = *(const float4*)&hb[(size_t)d * 512];
        e0 += al * h.x; e1 += al * h.y; e2 += al * h.z; e3 += al * h.w;
    }
    if (dp) {
        float4 v; v.x = e0; v.y = e1; v.z = e2; v.w = e3;
        *(float4*)&ered[c4] = v;
    }
    __syncthreads();
    if (!dp) {
        float4 p = *(const float4*)&ered[c4];
        float4 r; r.x = e0 + p.x; r.y = e1 + p.y; r.z = e2 + p.z; r.w = e3 + p.w;
        *(float4*)&out[b * 512 + c4] = r;
    }
}

extern "C" void kernel_launch(void* const* d_in, const int* in_sizes, int n_in,
                              void* d_out, int out_size, void* d_ws, size_t ws_size,
                              hipStream_t stream) {
    const float* h_tilde = (const float*)d_in[0];
    const float* c_t     = (const float*)d_in[1];
    const float* hist    = (const float*)d_in[2];
    const float* Waq     = (const float*)d_in[3];
    const float* Wah     = (const float*)d_in[4];
    const float* ba      = (const float*)d_in[5];
    const float* v_t     = (const float*)d_in[6];
    float* out = (float*)d_out;

    char* ws = (char*)d_ws;
    float*    qb     = (float*)ws;                               // 2 MB
    _Float16* W16    = (_Float16*)(ws + (2u << 20));             // 512 KB
    float*    logits = (float*)(ws + (3u << 20));                // 1 MB

    k_convertW<<<128, 256, 0, stream>>>(Wah, W16);
    k_qproj<<<256, 256, 0, stream>>>(h_tilde, c_t, Waq, ba, qb);
    k_logits<<<4096, 256, 0, stream>>>(hist, qb, W16, v_t, logits);
    k_softmax_et<<<1024, 256, 0, stream>>>(hist, logits, out);
}

// Round 11
// 391.716 us; speedup vs baseline: 1.8678x; 1.0580x over previous
//
#include <hip/hip_runtime.h>
#include <hip/hip_bf16.h>

#define HDIM 512
#define BDIM 1024
#define DDIM 256
#define MTOT (BDIM * DDIM)

typedef _Float16 half8 __attribute__((ext_vector_type(8)));
typedef float f32x4 __attribute__((ext_vector_type(4)));

__device__ __forceinline__ float ftanh(float x) {
    float e = __expf(2.0f * x);
    return 1.0f - 2.0f / (e + 1.0f);
}

__device__ __forceinline__ void gl_lds16(const _Float16* src, _Float16* dst) {
    __builtin_amdgcn_global_load_lds((const __attribute__((address_space(1))) void*)src,
                                     (__attribute__((address_space(3))) void*)dst,
                                     16, 0, 0);
}

// K0: Wah f32 [512][512] -> W16 fp16 chunked (R7 layout, measured 0 conflicts).
__global__ __launch_bounds__(256) void k_convertW(const float* __restrict__ Wah,
                                                  _Float16* __restrict__ W16) {
    int n = blockIdx.x * 256 + threadIdx.x;   // granule id, 32768 total
    int chunk = n >> 10, r = n & 1023;
    int kb = r >> 6, kp = (r >> 4) & 3, g = r & 15;
    const float* src = Wah + (size_t)(chunk * 16 + g) * 512 + kb * 32 + kp * 8;
    float4 v0 = *(const float4*)src;
    float4 v1 = *(const float4*)(src + 4);
    half8 h;
    h[0] = (_Float16)v0.x; h[1] = (_Float16)v0.y; h[2] = (_Float16)v0.z; h[3] = (_Float16)v0.w;
    h[4] = (_Float16)v1.x; h[5] = (_Float16)v1.y; h[6] = (_Float16)v1.z; h[7] = (_Float16)v1.w;
    *(half8*)&W16[(size_t)n * 8] = h;
}

// K1: qb[b,g] = concat(h_tilde,c_t)[b,:] . Waq[g,:] + ba[g]   (fp32)
__global__ __launch_bounds__(256) void k_qproj(const float* __restrict__ h_tilde,
                                               const float* __restrict__ c_t,
                                               const float* __restrict__ Waq,
                                               const float* __restrict__ ba,
                                               float* __restrict__ qb) {
    __shared__ float qs[4][1024];
    int t = threadIdx.x;
    int b0 = blockIdx.x * 4;
    #pragma unroll
    for (int p = 0; p < 4; p++) {
        int f4 = t + p * 256;
        int e = f4 * 4;
        int row = e >> 10, k = e & 1023;
        float4 v;
        if (k < 512) v = *(const float4*)&h_tilde[(b0 + row) * 512 + k];
        else         v = *(const float4*)&c_t[(b0 + row) * 512 + k - 512];
        *(float4*)&qs[row][k] = v;
    }
    __syncthreads();
    int g0 = t, g1 = t + 256;
    float acc0[4] = {0.f, 0.f, 0.f, 0.f};
    float acc1[4] = {0.f, 0.f, 0.f, 0.f};
    const float4* w0p = (const float4*)&Waq[(size_t)g0 * 1024];
    const float4* w1p = (const float4*)&Waq[(size_t)g1 * 1024];
    #pragma unroll 4
    for (int k4 = 0; k4 < 256; k4++) {
        float4 w0 = w0p[k4];
        float4 w1 = w1p[k4];
        #pragma unroll
        for (int bb = 0; bb < 4; bb++) {
            float4 q = *(const float4*)&qs[bb][k4 * 4];
            acc0[bb] += q.x * w0.x + q.y * w0.y + q.z * w0.z + q.w * w0.w;
            acc1[bb] += q.x * w1.x + q.y * w1.y + q.z * w1.z + q.w * w1.w;
        }
    }
    #pragma unroll
    for (int bb = 0; bb < 4; bb++) {
        qb[(b0 + bb) * 512 + g0] = acc0[bb] + ba[g0];
        qb[(b0 + bb) * 512 + g1] = acc1[bb] + ba[g1];
    }
}

// K2: R10 structure (64 rows x full N, 4 waves, afr[16]=64 VGPR, 4 blocks/CU)
// + FUSED partial softmax & partial e_t epilogue (flash-style):
//   writes logits, and per-block (m_blk, s_blk, e_blk[512] unnormalized).
__global__ __launch_bounds__(256, 4) void k_logits(const float* __restrict__ hist,
                                                   const float* __restrict__ qb,
                                                   const _Float16* __restrict__ W16,
                                                   const float* __restrict__ v_t,
                                                   float* __restrict__ logits,
                                                   float* __restrict__ eparts,
                                                   float* __restrict__ ms) {
    __shared__ _Float16 Wb[2][8192];   // 16 KB each; reused as e_t scratch after loop
    __shared__ float qbs[512];
    __shared__ float vsh[512];
    __shared__ float lsh[64];

    int t = threadIdx.x;
    int w = t >> 6, lane = t & 63, l15 = lane & 15, l4 = lane >> 4;
    int bx = blockIdx.x;
    size_t m_base = (size_t)bx * 64;
    int b = bx >> 2;                   // 64-row tile within one b (D=256)

    qbs[t] = qb[b * 512 + t];
    qbs[t + 256] = qb[b * 512 + 256 + t];
    vsh[t] = v_t[t];
    vsh[t + 256] = v_t[256 + t];

    // issue DMA for chunk 0 (completes during X-load phase)
    #pragma unroll
    for (int sg = 0; sg < 4; sg++)
        gl_lds16(W16 + ((size_t)(w * 4 + sg) * 64 + lane) * 8,
                 &Wb[0][(w * 4 + sg) * 512]);

    // X-load: afr[kb] = hist[m_base + w*16 + l15][kb*32 + l4*8 .. +8] as fp16
    half8 afr[16];
    const float* xb = hist + (m_base + w * 16 + l15) * 512 + l4 * 8;
    #pragma unroll
    for (int kb = 0; kb < 16; kb++) {
        const float* p = xb + kb * 32;
        float4 v0 = *(const float4*)p;
        float4 v1 = *(const float4*)(p + 4);
        half8 h;
        h[0] = (_Float16)v0.x; h[1] = (_Float16)v0.y; h[2] = (_Float16)v0.z; h[3] = (_Float16)v0.w;
        h[4] = (_Float16)v1.x; h[5] = (_Float16)v1.y; h[6] = (_Float16)v1.z; h[7] = (_Float16)v1.w;
        afr[kb] = h;
    }

    float S[4] = {0.f, 0.f, 0.f, 0.f};

    __syncthreads();   // drains DMA chunk 0 + qbs/vsh stores

    const _Float16* bufbase0 = &Wb[0][lane * 8];
    const _Float16* bufbase1 = &Wb[1][lane * 8];

    for (int c = 0; c < 32; c++) {
        int cur = c & 1;
        if (c < 31) {
            const _Float16* wc = W16 + (size_t)(c + 1) * 8192;
            _Float16* wd = Wb[cur ^ 1];
            #pragma unroll
            for (int sg = 0; sg < 4; sg++)
                gl_lds16(wc + ((size_t)(w * 4 + sg) * 64 + lane) * 8,
                         &wd[(w * 4 + sg) * 512]);
        }
        const _Float16* bufp = cur ? bufbase1 : bufbase0;
        f32x4 tac = (f32x4){0.f, 0.f, 0.f, 0.f};
        __builtin_amdgcn_s_setprio(1);
        #pragma unroll
        for (int kb = 0; kb < 16; kb++) {
            half8 bf = *(const half8*)(bufp + kb * 512);
            tac = __builtin_amdgcn_mfma_f32_16x16x32_f16(afr[kb], bf, tac, 0, 0, 0);
        }
        __builtin_amdgcn_s_setprio(0);
        float qv = qbs[c * 16 + l15];
        float vv = vsh[c * 16 + l15];
        #pragma unroll
        for (int j = 0; j < 4; j++)
            S[j] += ftanh(tac[j] + qv) * vv;
        __syncthreads();   // DMA(c+1) done; all waves done with buf[cur]
    }

    // ---- logits: reduce over l15; row = w*16 + l4*4 + j ----
    #pragma unroll
    for (int j = 0; j < 4; j++) {
        float s = S[j];
        s += __shfl_xor(s, 1, 64);
        s += __shfl_xor(s, 2, 64);
        s += __shfl_xor(s, 4, 64);
        s += __shfl_xor(s, 8, 64);
        if (l15 == 0) {
            logits[m_base + w * 16 + l4 * 4 + j] = s;
            lsh[w * 16 + l4 * 4 + j] = s;
        }
    }
    __syncthreads();   // lsh complete; all waves past Wb reads

    // ---- block-local softmax stats over the 64 rows ----
    float lv = lsh[lane];              // 64 distinct values per wave
    float mb = lv;
    mb = fmaxf(mb, __shfl_xor(mb, 1, 64));
    mb = fmaxf(mb, __shfl_xor(mb, 2, 64));
    mb = fmaxf(mb, __shfl_xor(mb, 4, 64));
    mb = fmaxf(mb, __shfl_xor(mb, 8, 64));
    mb = fmaxf(mb, __shfl_xor(mb, 16, 64));
    mb = fmaxf(mb, __shfl_xor(mb, 32, 64));
    float eb = __expf(lv - mb);
    float sb = eb;
    sb += __shfl_xor(sb, 1, 64);
    sb += __shfl_xor(sb, 2, 64);
    sb += __shfl_xor(sb, 4, 64);
    sb += __shfl_xor(sb, 8, 64);
    sb += __shfl_xor(sb, 16, 64);
    sb += __shfl_xor(sb, 32, 64);

    // ---- partial e_t from afr: e_blk[h] = sum_rows exp(l-mb) * x16[row][h] ----
    // lane holds row w*16 + l15 (k-slice l4); reduce over l15 groups.
    float coef = __expf(lsh[w * 16 + l15] - mb);
    float* ews = (float*)Wb;           // reuse 8 KB of Wb as [4][512] scratch
    #pragma unroll
    for (int kb = 0; kb < 16; kb++) {
        float ep[8];
        half8 x = afr[kb];
        #pragma unroll
        for (int e2 = 0; e2 < 8; e2++) ep[e2] = coef * (float)x[e2];
        #pragma unroll
        for (int e2 = 0; e2 < 8; e2++) {
            ep[e2] += __shfl_xor(ep[e2], 1, 64);
            ep[e2] += __shfl_xor(ep[e2], 2, 64);
            ep[e2] += __shfl_xor(ep[e2], 4, 64);
            ep[e2] += __shfl_xor(ep[e2], 8, 64);
        }
        if (l15 == 0) {
            #pragma unroll
            for (int e2 = 0; e2 < 8; e2++)
                ews[w * 512 + kb * 32 + l4 * 8 + e2] = ep[e2];
        }
    }
    __syncthreads();
    float v0 = ews[t] + ews[512 + t] + ews[1024 + t] + ews[1536 + t];
    float v1 = ews[256 + t] + ews[768 + t] + ews[1280 + t] + ews[1792 + t];
    eparts[(size_t)bx * 512 + t] = v0;
    eparts[(size_t)bx * 512 + 256 + t] = v1;
    if (t == 0) { ms[bx * 2] = mb; ms[bx * 2 + 1] = sb; }
}

// K3: combine 4 block-partials per b (exact flash-combine) -> alpha + e_t.
__global__ __launch_bounds__(256) void k_comb(const float* __restrict__ logits,
                                              const float* __restrict__ eparts,
                                              const float* __restrict__ ms,
                                              float* __restrict__ out) {
    int b = blockIdx.x, t = threadIdx.x;
    float m0 = ms[(4 * b + 0) * 2], s0 = ms[(4 * b + 0) * 2 + 1];
    float m1 = ms[(4 * b + 1) * 2], s1 = ms[(4 * b + 1) * 2 + 1];
    float m2 = ms[(4 * b + 2) * 2], s2 = ms[(4 * b + 2) * 2 + 1];
    float m3 = ms[(4 * b + 3) * 2], s3 = ms[(4 * b + 3) * 2 + 1];
    float m = fmaxf(fmaxf(m0, m1), fmaxf(m2, m3));
    float w0 = __expf(m0 - m), w1 = __expf(m1 - m);
    float w2 = __expf(m2 - m), w3 = __expf(m3 - m);
    float Sb = w0 * s0 + w1 * s1 + w2 * s2 + w3 * s3;
    // alpha
    float l = logits[b * 256 + t];
    out[BDIM * HDIM + b * 256 + t] = __expf(l - m) / Sb;
    // e_t
    const float* ep = eparts + (size_t)(4 * b) * 512;
    float a0 = w0 * ep[t] + w1 * ep[512 + t] + w2 * ep[1024 + t] + w3 * ep[1536 + t];
    float a1 = w0 * ep[256 + t] + w1 * ep[768 + t] + w2 * ep[1280 + t] + w3 * ep[1792 + t];
    out[b * 512 + t] = a0 / Sb;
    out[b * 512 + 256 + t] = a1 / Sb;
}

extern "C" void kernel_launch(void* const* d_in, const int* in_sizes, int n_in,
                              void* d_out, int out_size, void* d_ws, size_t ws_size,
                              hipStream_t stream) {
    const float* h_tilde = (const float*)d_in[0];
    const float* c_t     = (const float*)d_in[1];
    const float* hist    = (const float*)d_in[2];
    const float* Waq     = (const float*)d_in[3];
    const float* Wah     = (const float*)d_in[4];
    const float* ba      = (const float*)d_in[5];
    const float* v_t     = (const float*)d_in[6];
    float* out = (float*)d_out;

    char* ws = (char*)d_ws;
    float*    qb     = (float*)ws;                                // 2 MB
    _Float16* W16    = (_Float16*)(ws + (2u << 20));              // 512 KB
    float*    logits = (float*)(ws + (3u << 20));                 // 1 MB
    float*    eparts = (float*)(ws + (4u << 20));                 // 8 MB
    float*    ms     = (float*)(ws + (12u << 20));                // 32 KB

    k_convertW<<<128, 256, 0, stream>>>(Wah, W16);
    k_qproj<<<256, 256, 0, stream>>>(h_tilde, c_t, Waq, ba, qb);
    k_logits<<<4096, 256, 0, stream>>>(hist, qb, W16, v_t, logits, eparts, ms);
    k_comb<<<1024, 256, 0, stream>>>(logits, eparts, ms, out);
}

// Round 12
// 382.899 us; speedup vs baseline: 1.9108x; 1.0230x over previous
//
#include <hip/hip_runtime.h>
#include <hip/hip_bf16.h>

#define HDIM 512
#define BDIM 1024
#define DDIM 256
#define MTOT (BDIM * DDIM)

typedef _Float16 half8 __attribute__((ext_vector_type(8)));
typedef float f32x4 __attribute__((ext_vector_type(4)));

__device__ __forceinline__ float ftanh(float x) {
    // tanh(x) = 1 - 2/(exp(2x)+1); raw v_rcp (rel err ~1e-6 vs 0.094 threshold)
    float e = __expf(2.0f * x);
    float d = e + 1.0f;
    float r;
    asm("v_rcp_f32 %0, %1" : "=v"(r) : "v"(d));
    return 1.0f - 2.0f * r;
}

__device__ __forceinline__ void gl_lds16(const _Float16* src, _Float16* dst) {
    __builtin_amdgcn_global_load_lds((const __attribute__((address_space(1))) void*)src,
                                     (__attribute__((address_space(3))) void*)dst,
                                     16, 0, 0);
}

// K0 (merged): blocks 0..255 = qproj, blocks 256..383 = Wah->W16 convert.
// W16 chunked layout (R7, measured 0 bank conflicts): chunk c = g-cols
// [c*16,c*16+16), granule kb*64+kp*16+g holds Wah[c*16+g][kb*32+kp*8..+8];
// B-frag for lane l sits at granule kb*64+l (1024 consecutive bytes/wave).
__global__ __launch_bounds__(256) void k_prep(const float* __restrict__ h_tilde,
                                              const float* __restrict__ c_t,
                                              const float* __restrict__ Waq,
                                              const float* __restrict__ ba,
                                              const float* __restrict__ Wah,
                                              float* __restrict__ qb,
                                              _Float16* __restrict__ W16) {
    __shared__ float qs[4][1024];
    int t = threadIdx.x;
    if (blockIdx.x >= 256) {
        // ---- convertW ----
        int n = (blockIdx.x - 256) * 256 + t;     // granule id, 32768 total
        int chunk = n >> 10, r = n & 1023;
        int kb = r >> 6, kp = (r >> 4) & 3, g = r & 15;
        const float* src = Wah + (size_t)(chunk * 16 + g) * 512 + kb * 32 + kp * 8;
        float4 v0 = *(const float4*)src;
        float4 v1 = *(const float4*)(src + 4);
        half8 h;
        h[0] = (_Float16)v0.x; h[1] = (_Float16)v0.y; h[2] = (_Float16)v0.z; h[3] = (_Float16)v0.w;
        h[4] = (_Float16)v1.x; h[5] = (_Float16)v1.y; h[6] = (_Float16)v1.z; h[7] = (_Float16)v1.w;
        *(half8*)&W16[(size_t)n * 8] = h;
        return;
    }
    // ---- qproj ----
    int b0 = blockIdx.x * 4;
    #pragma unroll
    for (int p = 0; p < 4; p++) {
        int f4 = t + p * 256;
        int e = f4 * 4;
        int row = e >> 10, k = e & 1023;
        float4 v;
        if (k < 512) v = *(const float4*)&h_tilde[(b0 + row) * 512 + k];
        else         v = *(const float4*)&c_t[(b0 + row) * 512 + k - 512];
        *(float4*)&qs[row][k] = v;
    }
    __syncthreads();
    int g0 = t, g1 = t + 256;
    float acc0[4] = {0.f, 0.f, 0.f, 0.f};
    float acc1[4] = {0.f, 0.f, 0.f, 0.f};
    const float4* w0p = (const float4*)&Waq[(size_t)g0 * 1024];
    const float4* w1p = (const float4*)&Waq[(size_t)g1 * 1024];
    #pragma unroll 4
    for (int k4 = 0; k4 < 256; k4++) {
        float4 w0 = w0p[k4];
        float4 w1 = w1p[k4];
        #pragma unroll
        for (int bb = 0; bb < 4; bb++) {
            float4 q = *(const float4*)&qs[bb][k4 * 4];
            acc0[bb] += q.x * w0.x + q.y * w0.y + q.z * w0.z + q.w * w0.w;
            acc1[bb] += q.x * w1.x + q.y * w1.y + q.z * w1.z + q.w * w1.w;
        }
    }
    #pragma unroll
    for (int bb = 0; bb < 4; bb++) {
        qb[(b0 + bb) * 512 + g0] = acc0[bb] + ba[g0];
        qb[(b0 + bb) * 512 + g1] = acc1[bb] + ba[g1];
    }
}

// K2: R11 structure (64 rows x full N, 4 waves, afr[16], 4 blocks/CU, fused
// flash-style partial softmax + partial e_t) + R12 changes:
//  - depth-4 X-load ring (restores memory-level parallelism at round start)
//  - per-block chunk-offset stagger (desyncs co-resident blocks' L2/LDS bursts)
__global__ __launch_bounds__(256, 4) void k_logits(const float* __restrict__ hist,
                                                   const float* __restrict__ qb,
                                                   const _Float16* __restrict__ W16,
                                                   const float* __restrict__ v_t,
                                                   float* __restrict__ logits,
                                                   float* __restrict__ eparts,
                                                   float* __restrict__ ms) {
    __shared__ _Float16 Wb[2][8192];   // 16 KB each; reused as e_t scratch after loop
    __shared__ float qbs[512];
    __shared__ float vsh[512];
    __shared__ float lsh[64];

    int t = threadIdx.x;
    int w = t >> 6, lane = t & 63, l15 = lane & 15, l4 = lane >> 4;
    int bx = blockIdx.x;
    size_t m_base = (size_t)bx * 64;
    int b = bx >> 2;                   // 64-row tile within one b (D=256)
    int off = ((bx >> 3) & 3) * 8;     // chunk-phase stagger

    qbs[t] = qb[b * 512 + t];
    qbs[t + 256] = qb[b * 512 + 256 + t];
    vsh[t] = v_t[t];
    vsh[t + 256] = v_t[256 + t];

    // issue DMA for first chunk (index `off`); completes during X-load phase
    #pragma unroll
    for (int sg = 0; sg < 4; sg++)
        gl_lds16(W16 + (size_t)off * 8192 + ((size_t)(w * 4 + sg) * 64 + lane) * 8,
                 &Wb[0][(w * 4 + sg) * 512]);

    // X-load with explicit depth-4 ring (32 VGPR transient, static slots):
    // afr[kb] = hist[m_base + w*16 + l15][kb*32 + l4*8 .. +8] as fp16
    half8 afr[16];
    const float* xb = hist + (m_base + w * 16 + l15) * 512 + l4 * 8;
    {
        float4 xr0[4], xr1[4];
        #pragma unroll
        for (int u = 0; u < 4; u++) {
            xr0[u] = *(const float4*)(xb + u * 32);
            xr1[u] = *(const float4*)(xb + u * 32 + 4);
        }
        #pragma unroll
        for (int kb = 0; kb < 16; kb++) {
            const int slot = kb & 3;
            float4 v0 = xr0[slot];
            float4 v1 = xr1[slot];
            if (kb + 4 < 16) {
                xr0[slot] = *(const float4*)(xb + (kb + 4) * 32);
                xr1[slot] = *(const float4*)(xb + (kb + 4) * 32 + 4);
            }
            half8 h;
            h[0] = (_Float16)v0.x; h[1] = (_Float16)v0.y; h[2] = (_Float16)v0.z; h[3] = (_Float16)v0.w;
            h[4] = (_Float16)v1.x; h[5] = (_Float16)v1.y; h[6] = (_Float16)v1.z; h[7] = (_Float16)v1.w;
            afr[kb] = h;
        }
    }

    float S[4] = {0.f, 0.f, 0.f, 0.f};

    __syncthreads();   // drains DMA first chunk + qbs/vsh stores

    const _Float16* bufbase0 = &Wb[0][lane * 8];
    const _Float16* bufbase1 = &Wb[1][lane * 8];

    for (int c = 0; c < 32; c++) {
        int cc = (c + off) & 31;
        int cur = c & 1;
        if (c < 31) {
            int cn = (cc + 1) & 31;
            const _Float16* wc = W16 + (size_t)cn * 8192;
            _Float16* wd = Wb[cur ^ 1];
            #pragma unroll
            for (int sg = 0; sg < 4; sg++)
                gl_lds16(wc + ((size_t)(w * 4 + sg) * 64 + lane) * 8,
                         &wd[(w * 4 + sg) * 512]);
        }
        float qv = qbs[cc * 16 + l15];
        float vv = vsh[cc * 16 + l15];
        const _Float16* bufp = cur ? bufbase1 : bufbase0;
        f32x4 tac = (f32x4){0.f, 0.f, 0.f, 0.f};
        __builtin_amdgcn_s_setprio(1);
        #pragma unroll
        for (int kb = 0; kb < 16; kb++) {
            half8 bf = *(const half8*)(bufp + kb * 512);
            tac = __builtin_amdgcn_mfma_f32_16x16x32_f16(afr[kb], bf, tac, 0, 0, 0);
        }
        __builtin_amdgcn_s_setprio(0);
        #pragma unroll
        for (int j = 0; j < 4; j++)
            S[j] += ftanh(tac[j] + qv) * vv;
        __syncthreads();   // DMA(next) done; all waves done with buf[cur]
    }

    // ---- logits: reduce over l15; row = w*16 + l4*4 + j ----
    #pragma unroll
    for (int j = 0; j < 4; j++) {
        float s = S[j];
        s += __shfl_xor(s, 1, 64);
        s += __shfl_xor(s, 2, 64);
        s += __shfl_xor(s, 4, 64);
        s += __shfl_xor(s, 8, 64);
        if (l15 == 0) {
            logits[m_base + w * 16 + l4 * 4 + j] = s;
            lsh[w * 16 + l4 * 4 + j] = s;
        }
    }
    __syncthreads();   // lsh complete; all waves past Wb reads

    // ---- block-local softmax stats over the 64 rows ----
    float lv = lsh[lane];
    float mb = lv;
    mb = fmaxf(mb, __shfl_xor(mb, 1, 64));
    mb = fmaxf(mb, __shfl_xor(mb, 2, 64));
    mb = fmaxf(mb, __shfl_xor(mb, 4, 64));
    mb = fmaxf(mb, __shfl_xor(mb, 8, 64));
    mb = fmaxf(mb, __shfl_xor(mb, 16, 64));
    mb = fmaxf(mb, __shfl_xor(mb, 32, 64));
    float eb = __expf(lv - mb);
    float sb = eb;
    sb += __shfl_xor(sb, 1, 64);
    sb += __shfl_xor(sb, 2, 64);
    sb += __shfl_xor(sb, 4, 64);
    sb += __shfl_xor(sb, 8, 64);
    sb += __shfl_xor(sb, 16, 64);
    sb += __shfl_xor(sb, 32, 64);

    // ---- partial e_t from afr: e_blk[h] = sum_rows exp(l-mb) * x16[row][h] ----
    float coef = __expf(lsh[w * 16 + l15] - mb);
    float* ews = (float*)Wb;           // reuse 8 KB of Wb as [4][512] scratch
    #pragma unroll
    for (int kb = 0; kb < 16; kb++) {
        float ep[8];
        half8 x = afr[kb];
        #pragma unroll
        for (int e2 = 0; e2 < 8; e2++) ep[e2] = coef * (float)x[e2];
        #pragma unroll
        for (int e2 = 0; e2 < 8; e2++) {
            ep[e2] += __shfl_xor(ep[e2], 1, 64);
            ep[e2] += __shfl_xor(ep[e2], 2, 64);
            ep[e2] += __shfl_xor(ep[e2], 4, 64);
            ep[e2] += __shfl_xor(ep[e2], 8, 64);
        }
        if (l15 == 0) {
            #pragma unroll
            for (int e2 = 0; e2 < 8; e2++)
                ews[w * 512 + kb * 32 + l4 * 8 + e2] = ep[e2];
        }
    }
    __syncthreads();
    float v0 = ews[t] + ews[512 + t] + ews[1024 + t] + ews[1536 + t];
    float v1 = ews[256 + t] + ews[768 + t] + ews[1280 + t] + ews[1792 + t];
    eparts[(size_t)bx * 512 + t] = v0;
    eparts[(size_t)bx * 512 + 256 + t] = v1;
    if (t == 0) { ms[bx * 2] = mb; ms[bx * 2 + 1] = sb; }
}

// K3: combine 4 block-partials per b (exact flash-combine) -> alpha + e_t.
__global__ __launch_bounds__(256) void k_comb(const float* __restrict__ logits,
                                              const float* __restrict__ eparts,
                                              const float* __restrict__ ms,
                                              float* __restrict__ out) {
    int b = blockIdx.x, t = threadIdx.x;
    float m0 = ms[(4 * b + 0) * 2], s0 = ms[(4 * b + 0) * 2 + 1];
    float m1 = ms[(4 * b + 1) * 2], s1 = ms[(4 * b + 1) * 2 + 1];
    float m2 = ms[(4 * b + 2) * 2], s2 = ms[(4 * b + 2) * 2 + 1];
    float m3 = ms[(4 * b + 3) * 2], s3 = ms[(4 * b + 3) * 2 + 1];
    float m = fmaxf(fmaxf(m0, m1), fmaxf(m2, m3));
    float w0 = __expf(m0 - m), w1 = __expf(m1 - m);
    float w2 = __expf(m2 - m), w3 = __expf(m3 - m);
    float Sb = w0 * s0 + w1 * s1 + w2 * s2 + w3 * s3;
    float l = logits[b * 256 + t];
    out[BDIM * HDIM + b * 256 + t] = __expf(l - m) / Sb;   // alpha
    const float* ep = eparts + (size_t)(4 * b) * 512;
    float a0 = w0 * ep[t] + w1 * ep[512 + t] + w2 * ep[1024 + t] + w3 * ep[1536 + t];
    float a1 = w0 * ep[256 + t] + w1 * ep[768 + t] + w2 * ep[1280 + t] + w3 * ep[1792 + t];
    out[b * 512 + t] = a0 / Sb;                            // e_t
    out[b * 512 + 256 + t] = a1 / Sb;
}

extern "C" void kernel_launch(void* const* d_in, const int* in_sizes, int n_in,
                              void* d_out, int out_size, void* d_ws, size_t ws_size,
                              hipStream_t stream) {
    const float* h_tilde = (const float*)d_in[0];
    const float* c_t     = (const float*)d_in[1];
    const float* hist    = (const float*)d_in[2];
    const float* Waq     = (const float*)d_in[3];
    const float* Wah     = (const float*)d_in[4];
    const float* ba      = (const float*)d_in[5];
    const float* v_t     = (const float*)d_in[6];
    float* out = (float*)d_out;

    char* ws = (char*)d_ws;
    float*    qb     = (float*)ws;                                // 2 MB
    _Float16* W16    = (_Float16*)(ws + (2u << 20));              // 512 KB
    float*    logits = (float*)(ws + (3u << 20));                 // 1 MB
    float*    eparts = (float*)(ws + (4u << 20));                 // 8 MB
    float*    ms     = (float*)(ws + (12u << 20));                // 32 KB

    k_prep<<<384, 256, 0, stream>>>(h_tilde, c_t, Waq, ba, Wah, qb, W16);
    k_logits<<<4096, 256, 0, stream>>>(hist, qb, W16, v_t, logits, eparts, ms);
    k_comb<<<1024, 256, 0, stream>>>(logits, eparts, ms, out);
}